// Round 12
// baseline (160.907 us; speedup 1.0000x reference)
//
#include <hip/hip_runtime.h>
#include <math.h>

#define NB 2
#define NO 512
#define NQ 512
#define OUT_DIM 128
#define LPAD 516   // logits row pitch (floats); %32==4 bank spread, %4==0 for float4

typedef __attribute__((ext_vector_type(8))) short short8;   // 8 bf16
typedef __attribute__((ext_vector_type(4))) float f32x4;    // MFMA acc
typedef float v2f __attribute__((ext_vector_type(2)));

__device__ __forceinline__ float softplus_f(float x) {
  return x > 0.0f ? x + __logf(1.0f + __expf(-x)) : __logf(1.0f + __expf(x));
}
__device__ __forceinline__ unsigned short bf16_rne(float f) {
  unsigned u = __float_as_uint(f);
  unsigned r = u + 0x7FFFu + ((u >> 16) & 1u);
  return (unsigned short)(r >> 16);
}
__device__ __forceinline__ float bf16_to_f32(unsigned short h) {
  return __uint_as_float(((unsigned)h) << 16);
}

#if defined(__has_builtin)
#if __has_builtin(__builtin_amdgcn_cvt_pk_bf16_f32)
#define HAS_CVT_PK_BF16 1
#endif
#endif

__device__ __forceinline__ unsigned pack_bf2(float x, float y) {
#ifdef HAS_CVT_PK_BF16
  auto r = __builtin_amdgcn_cvt_pk_bf16_f32(x, y);
  unsigned u; __builtin_memcpy(&u, &r, 4);
  return u;
#else
  unsigned ux = __float_as_uint(x);
  unsigned uy = __float_as_uint(y);
  ux = ux + 0x7FFFu + ((ux >> 16) & 1u);
  uy = uy + 0x7FFFu + ((uy >> 16) & 1u);
  return (ux >> 16) | (uy & 0xFFFF0000u);
#endif
}
__device__ __forceinline__ v2f unpk_bf2(unsigned u) {
  v2f r; r.x = __uint_as_float(u << 16); r.y = __uint_as_float(u & 0xFFFF0000u);
  return r;
}
__device__ __forceinline__ v2f splat2(float x) { v2f r; r.x = x; r.y = x; return r; }
__device__ __forceinline__ v2f fma2(v2f a, v2f b, v2f c) { return __builtin_elementwise_fma(a, b, c); }
__device__ __forceinline__ v2f max2(v2f a, v2f b) { return __builtin_elementwise_max(a, b); }

// ---------------------------------------------------------------------------
// Prep: 513 blocks x 1024 threads.
// 0..255: fused 2-layer MLP (4 rows, k-split 4) -> V bf16.
// 256..511: AO bf16, 4 o-rows/block.
// 512: kw2 MFMA B-fragments, split bf16 hi/lo -> global (8 KB each).
__global__ __launch_bounds__(1024) void prep_kernel(
    const float* __restrict__ h_obs, const float* __restrict__ fw1,
    const float* __restrict__ fb1, const float* __restrict__ fw2,
    const float* __restrict__ fb2, const float* __restrict__ pos_obs,
    const float* __restrict__ kw1, const float* __restrict__ kw2,
    unsigned short* __restrict__ V_bf, unsigned short* __restrict__ AO_bf,
    unsigned short* __restrict__ BFhi, unsigned short* __restrict__ BFlo)
{
  if (blockIdx.x < 256) {
    __shared__ float s_red[4][4][256];
    __shared__ float s_hid[4][256];
    const int n  = threadIdx.x & 255;
    const int ks = threadIdx.x >> 8;
    const int r0 = blockIdx.x * 4;
    const int k0 = ks * 64;
    float a0 = 0.f, a1 = 0.f, a2 = 0.f, a3 = 0.f;
    #pragma unroll 8
    for (int kk = 0; kk < 64; ++kk) {
      int k = k0 + kk;
      float w = fw1[k * 256 + n];
      a0 = fmaf(h_obs[(r0 + 0) * 256 + k], w, a0);
      a1 = fmaf(h_obs[(r0 + 1) * 256 + k], w, a1);
      a2 = fmaf(h_obs[(r0 + 2) * 256 + k], w, a2);
      a3 = fmaf(h_obs[(r0 + 3) * 256 + k], w, a3);
    }
    s_red[ks][0][n] = a0; s_red[ks][1][n] = a1;
    s_red[ks][2][n] = a2; s_red[ks][3][n] = a3;
    __syncthreads();
    if (ks == 0) {
      float bb = fb1[n];
      #pragma unroll
      for (int r = 0; r < 4; ++r) {
        float v = s_red[0][r][n] + s_red[1][r][n] + s_red[2][r][n] + s_red[3][r][n] + bb;
        s_hid[r][n] = fmaxf(v, 0.f);
      }
    }
    __syncthreads();
    float c0 = 0.f, c1 = 0.f, c2 = 0.f, c3 = 0.f;
    #pragma unroll 8
    for (int kk = 0; kk < 64; ++kk) {
      int k = k0 + kk;
      float w = fw2[k * 256 + n];
      c0 = fmaf(s_hid[0][k], w, c0);
      c1 = fmaf(s_hid[1][k], w, c1);
      c2 = fmaf(s_hid[2][k], w, c2);
      c3 = fmaf(s_hid[3][k], w, c3);
    }
    __syncthreads();
    s_red[ks][0][n] = c0; s_red[ks][1][n] = c1;
    s_red[ks][2][n] = c2; s_red[ks][3][n] = c3;
    __syncthreads();
    if (ks == 0) {
      float bb = fb2[n];
      #pragma unroll
      for (int r = 0; r < 4; ++r) {
        float v = s_red[0][r][n] + s_red[1][r][n] + s_red[2][r][n] + s_red[3][r][n] + bb;
        V_bf[(size_t)(r0 + r) * 256 + n] = bf16_rne(v);
      }
    }
  } else if (blockIdx.x < 512) {
    const int i  = blockIdx.x - 256;
    const int b  = i >> 7;
    const int og = i & 127;
    const int ol = threadIdx.x >> 8;
    const int j  = threadIdx.x & 255;
    const int o  = og * 4 + ol;
    float c0 = kw1[3 * 256 + j] - kw1[6 * 256 + j];
    float c1 = kw1[4 * 256 + j] - kw1[7 * 256 + j];
    float c2 = kw1[5 * 256 + j] - kw1[8 * 256 + j];
    const float* p = pos_obs + ((size_t)(b * NO + o)) * 3;
    AO_bf[(size_t)(b * NO + o) * 256 + j] =
        bf16_rne(fmaf(p[0], c0, fmaf(p[1], c1, p[2] * c2)));
  } else {
    const int t = threadIdx.x;
    if (t < 512) {
      const int kstep = t >> 6, lane = t & 63;
      const int nh = lane & 15;
      const int kb_ = kstep * 32 + ((lane >> 4) & 3) * 8;
      short8 hi8, lo8;
      #pragma unroll
      for (int i = 0; i < 8; ++i) {
        float v = (nh < 8) ? kw2[(kb_ + i) * 8 + nh] : 0.f;
        unsigned short h = bf16_rne(v);
        hi8[i] = (short)h;
        lo8[i] = (short)bf16_rne(v - bf16_to_f32(h));
      }
      ((short8*)BFhi)[kstep * 64 + lane] = hi8;
      ((short8*)BFlo)[kstep * 64 + lane] = lo8;
    }
  }
}

// ---------------------------------------------------------------------------
// Fused attention + out_proj. QT=1, 1024 blocks x 512 threads (8 waves).
// LDS ~20 KB -> 4 blocks/CU -> 32 waves/CU (8/SIMD): full occupancy.
__global__ __launch_bounds__(512) void attn_fused(
    const unsigned short* __restrict__ V_bf,   // (B*NO, 256) bf16
    const unsigned short* __restrict__ AO_bf,  // (B*NO, 256) bf16
    const short8* __restrict__ BFhi,           // [kstep*64+lane]
    const short8* __restrict__ BFlo,
    const float* __restrict__ kw1,       // (9, 256)
    const float* __restrict__ kb1,       // (256)
    const float* __restrict__ kb2,       // (8)
    const float* __restrict__ log_sigma, // (8)
    const float* __restrict__ pos_obs,   // (B*NO, 3)
    const float* __restrict__ pos_query, // (B*NQ, 3)
    const float* __restrict__ ow, const float* __restrict__ obias,
    const float* __restrict__ vw, const float* __restrict__ vbias,
    float* __restrict__ out)
{
  __shared__ float s_logits[8 * LPAD];    // 16,512 B (s_pred overlays)
  __shared__ float s_aq[256];             // 1 KB
  __shared__ float s_hv[2][256];          // 2 KB
  __shared__ float s_sum[8];
  __shared__ float s_invs2[8];
  __shared__ float s_kb2v[8];
  float* s_pred = s_logits;               // [ks][mode][128] after logits die

  const int t  = threadIdx.x;
  const int bq = blockIdx.x;
  const int b  = bq >> 9;

  // ---- prologue -----------------------------------------------------------
  const float pqx = pos_query[bq * 3 + 0];
  const float pqy = pos_query[bq * 3 + 1];
  const float pqz = pos_query[bq * 3 + 2];
  if (t < 256) {
    const int j = t;
    float c0 = kw1[0 * 256 + j] + kw1[6 * 256 + j];
    float c1 = kw1[1 * 256 + j] + kw1[7 * 256 + j];
    float c2 = kw1[2 * 256 + j] + kw1[8 * 256 + j];
    s_aq[j] = fmaf(pqx, c0, fmaf(pqy, c1, fmaf(pqz, c2, kb1[j])));
  }
  if (t < 8) {
    float s = __expf(log_sigma[t]);
    s_invs2[t] = 1.0f / (s * s + 1e-6f);
    s_kb2v[t]  = kb2[t];
  }
  __syncthreads();                                           // B1

  // ---- rbf prefill, o = t -------------------------------------------------
  {
    const int o = t;
    const float* p = pos_obs + (size_t)(b * NO + o) * 3;
    float r0 = pqx - p[0], r1 = pqy - p[1], r2 = pqz - p[2];
    float d2 = r0 * r0 + r1 * r1 + r2 * r2;
    #pragma unroll
    for (int h = 0; h < 8; ++h)
      s_logits[h * LPAD + o] = __logf(__expf(-d2 * s_invs2[h]) + 1e-8f) + s_kb2v[h];
  }

  // ---- phase 1: MFMA delta (single q), B-frags from global ----------------
  {
    const int wave = t >> 6, lane = t & 63;
    const int quad = lane >> 4, mrow = lane & 15;
    const int tb   = wave * 4;                   // 4 o-tiles per wave
    f32x4 C[4];
    #pragma unroll
    for (int jt = 0; jt < 4; ++jt) C[jt] = (f32x4){0.f, 0.f, 0.f, 0.f};

    for (int kstep = 0; kstep < 8; ++kstep) {
      const int koff = kstep * 32 + quad * 8;
      const v2f* aqp = (const v2f*)(s_aq + koff);
      v2f aq[4];
      #pragma unroll
      for (int i = 0; i < 4; ++i) aq[i] = aqp[i];
      short8 bhi = BFhi[kstep * 64 + lane];
      short8 blo = BFlo[kstep * 64 + lane];
      #pragma unroll
      for (int jt = 0; jt < 4; ++jt) {
        const int o = (tb + jt) * 16 + mrow;
        int4 u = *(const int4*)(AO_bf + ((size_t)(b * NO + o) << 8) + koff);
        v2f z = splat2(0.f);
        v2f h0 = max2(aq[0] + unpk_bf2((unsigned)u.x), z);
        v2f h1 = max2(aq[1] + unpk_bf2((unsigned)u.y), z);
        v2f h2 = max2(aq[2] + unpk_bf2((unsigned)u.z), z);
        v2f h3 = max2(aq[3] + unpk_bf2((unsigned)u.w), z);
        int4 af;
        af.x = (int)pack_bf2(h0.x, h0.y); af.y = (int)pack_bf2(h1.x, h1.y);
        af.z = (int)pack_bf2(h2.x, h2.y); af.w = (int)pack_bf2(h3.x, h3.y);
        short8 a = __builtin_bit_cast(short8, af);
        C[jt] = __builtin_amdgcn_mfma_f32_16x16x32_bf16(a, bhi, C[jt], 0, 0, 0);
        C[jt] = __builtin_amdgcn_mfma_f32_16x16x32_bf16(a, blo, C[jt], 0, 0, 0);
      }
    }
    __syncthreads();   // prefill visible before += epilogue        // B2

    const int h = lane & 15;
    if (h < 8) {
      #pragma unroll
      for (int jt = 0; jt < 4; ++jt) {
        const int ob = (tb + jt) * 16 + quad * 4;
        #pragma unroll
        for (int r = 0; r < 4; ++r)
          s_logits[h * LPAD + ob + r] += C[jt][r];
      }
    }
  }
  __syncthreads();                                           // B3

  // ---- phase 2: softmax, wave w owns head h = w ---------------------------
  {
    const int h = t >> 6, lane = t & 63;
    float* pl = &s_logits[h * LPAD];
    float l[8];
    float m = -1e30f;
    #pragma unroll
    for (int k = 0; k < 8; ++k) {
      l[k] = pl[k * 64 + lane];
      m = fmaxf(m, l[k]);
    }
    #pragma unroll
    for (int off = 32; off >= 1; off >>= 1) m = fmaxf(m, __shfl_xor(m, off, 64));
    float s = 0.f;
    #pragma unroll
    for (int k = 0; k < 8; ++k) {
      float p = __expf(l[k] - m);
      pl[k * 64 + lane] = p;
      s += p;
    }
    #pragma unroll
    for (int off = 32; off >= 1; off >>= 1) s += __shfl_xor(s, off, 64);
    if (lane == 0) s_sum[h] = s;
  }
  __syncthreads();                                           // B4

  // ---- phase 3: PV + P V^2; o-slices combined via shfl --------------------
  {
    const int h    = t >> 6;             // wave = head
    const int lane = t & 63;
    const int oq   = lane >> 2;          // 16 o-slices of 32
    const int dg   = lane & 3;           // 4 d-octets of 8
    const unsigned short* vb_ = V_bf + ((size_t)(b * NO) << 8) + h * 32 + dg * 8;
    const float* P = &s_logits[h * LPAD + oq * 32];
    v2f s1[4], s2[4];
    #pragma unroll
    for (int i = 0; i < 4; ++i) { s1[i] = splat2(0.f); s2[i] = splat2(0.f); }
    const int o0 = oq * 32;
    #pragma unroll 2
    for (int oi = 0; oi < 32; oi += 4) {
      float4 pv = *(const float4*)&P[oi];       // ds_read_b128 broadcast
      #pragma unroll
      for (int i = 0; i < 4; ++i) {
        const int o = o0 + oi + i;
        uint4 vv = *(const uint4*)(vb_ + ((size_t)o << 8));
        v2f p = splat2((&pv.x)[i]);
        v2f v0 = unpk_bf2(vv.x), v1 = unpk_bf2(vv.y);
        v2f v2 = unpk_bf2(vv.z), v3 = unpk_bf2(vv.w);
        s1[0] = fma2(p, v0, s1[0]); s1[1] = fma2(p, v1, s1[1]);
        s1[2] = fma2(p, v2, s1[2]); s1[3] = fma2(p, v3, s1[3]);
        v2f t0 = p * v0, t1 = p * v1, t2 = p * v2, t3 = p * v3;
        s2[0] = fma2(t0, v0, s2[0]); s2[1] = fma2(t1, v1, s2[1]);
        s2[2] = fma2(t2, v2, s2[2]); s2[3] = fma2(t3, v3, s2[3]);
      }
    }
    // combine 16 o-slices: oq lives in lane bits 2..5
    #pragma unroll
    for (int mask = 4; mask <= 32; mask <<= 1) {
      #pragma unroll
      for (int i = 0; i < 4; ++i) {
        s1[i].x += __shfl_xor(s1[i].x, mask, 64);
        s1[i].y += __shfl_xor(s1[i].y, mask, 64);
        s2[i].x += __shfl_xor(s2[i].x, mask, 64);
        s2[i].y += __shfl_xor(s2[i].y, mask, 64);
      }
    }
    if (oq == 0) {
      float inv = 1.0f / s_sum[h];
      #pragma unroll
      for (int i = 0; i < 4; ++i) {
        float m1x = s1[i].x * inv, m1y = s1[i].y * inv;
        float vax = fmaxf(s2[i].x * inv - m1x * m1x, 0.f);
        float vay = fmaxf(s2[i].y * inv - m1y * m1y, 0.f);
        const int d = dg * 8 + 2 * i;
        s_hv[0][h * 32 + d]     = m1x;
        s_hv[0][h * 32 + d + 1] = m1y;
        s_hv[1][h * 32 + d]     = vax;
        s_hv[1][h * 32 + d + 1] = vay;
      }
    }
  }
  __syncthreads();                                           // B5

  // ---- phase 4: out_proj, k-split 2 (s_pred overlays dead logits) ---------
  {
    const int ks = t >> 8, mode = (t >> 7) & 1, n = t & 127;
    const float* W = mode ? vw : ow;
    const float* X = s_hv[mode];
    float acc = 0.f;
    const int k0 = ks * 128;
    #pragma unroll 4
    for (int k = k0; k < k0 + 128; k += 4) {
      float4 x = *(const float4*)&X[k];
      acc = fmaf(x.x, W[(k + 0) * 128 + n], acc);
      acc = fmaf(x.y, W[(k + 1) * 128 + n], acc);
      acc = fmaf(x.z, W[(k + 2) * 128 + n], acc);
      acc = fmaf(x.w, W[(k + 3) * 128 + n], acc);
    }
    s_pred[(ks * 2 + mode) * 128 + n] = acc;
  }
  __syncthreads();                                           // B6
  if (t < 256) {
    const int mode = t >> 7, n = t & 127;
    float v = s_pred[mode * 128 + n] + s_pred[(2 + mode) * 128 + n]
            + (mode ? vbias[n] : obias[n]);
    if (mode) v = softplus_f(v);
    out[(size_t)mode * (NB * NQ * OUT_DIM) + (size_t)bq * OUT_DIM + n] = v;
  }
}

// ---------------------------------------------------------------------------
extern "C" void kernel_launch(void* const* d_in, const int* in_sizes, int n_in,
                              void* d_out, int out_size, void* d_ws, size_t ws_size,
                              hipStream_t stream)
{
  const float* h_obs     = (const float*)d_in[0];
  const float* pos_obs   = (const float*)d_in[1];
  const float* pos_query = (const float*)d_in[2];
  const float* fw1       = (const float*)d_in[3];
  const float* fb1       = (const float*)d_in[4];
  const float* fw2       = (const float*)d_in[5];
  const float* fb2       = (const float*)d_in[6];
  const float* log_sigma = (const float*)d_in[7];
  const float* kw1       = (const float*)d_in[8];
  const float* kb1       = (const float*)d_in[9];
  const float* kw2       = (const float*)d_in[10];
  const float* kb2       = (const float*)d_in[11];
  const float* ow        = (const float*)d_in[12];
  const float* ob        = (const float*)d_in[13];
  const float* vw        = (const float*)d_in[14];
  const float* vb        = (const float*)d_in[15];

  float* out = (float*)d_out;
  unsigned short* ws = (unsigned short*)d_ws;

  unsigned short* V_bf  = ws;            // 262144 ushort
  unsigned short* AO_bf = ws + 262144;   // 262144 ushort
  unsigned short* BFhi  = ws + 524288;   // 4096 ushort
  unsigned short* BFlo  = ws + 528384;   // 4096 ushort

  prep_kernel<<<513, 1024, 0, stream>>>(h_obs, fw1, fb1, fw2, fb2,
                                        pos_obs, kw1, kw2, V_bf, AO_bf,
                                        BFhi, BFlo);
  attn_fused<<<NB * NQ, 512, 0, stream>>>(V_bf, AO_bf,
                                          (const short8*)BFhi, (const short8*)BFlo,
                                          kw1, kb1, kb2, log_sigma,
                                          pos_obs, pos_query,
                                          ow, ob, vw, vb, out);
}